// Round 5
// baseline (3843.848 us; speedup 1.0000x reference)
//
#include <hip/hip_runtime.h>
#include <hip/hip_bf16.h>
#include <cstdint>

#define HDIM 128

typedef __bf16 bf16x8 __attribute__((ext_vector_type(8)));
typedef unsigned short usx8 __attribute__((ext_vector_type(8)));
typedef float fx4 __attribute__((ext_vector_type(4)));

__device__ __forceinline__ float bf2f(unsigned short u) {
    unsigned int x = ((unsigned int)u) << 16;
    return __uint_as_float(x);
}
__device__ __forceinline__ unsigned short f2bf(float f) {
    unsigned int x = __float_as_uint(f);
    x += 0x7fffu + ((x >> 16) & 1u);
    return (unsigned short)(x >> 16);
}

__device__ __forceinline__ void detect_local(const unsigned int* xw, const unsigned int* eiw,
                                             int& f0, int& f1) {
    int sane = 0;
    for (int k = 0; k < 64; k++) {
        unsigned int w = xw[k];
        unsigned short ss[2] = {(unsigned short)(w & 0xffffu), (unsigned short)(w >> 16)};
        for (int q = 0; q < 2; q++) {
            int e = (ss[q] >> 7) & 0xFF;
            if ((ss[q] & 0x7fffu) == 0 || (e >= 100 && e <= 140)) sane++;
        }
    }
    f0 = (sane >= 110) ? 1 : 0;
    int zeros = 0;
    for (int k = 1; k < 64; k += 2)
        if (eiw[k] == 0) zeros++;
    f1 = (zeros >= 24) ? 1 : 0;
}

struct ParamTab {
    const void* p[15];
    int n[15];
    int off[15];
};

// ---------------- phase1: hist + param-convert + gbounds + repack + init ----------------
__global__ void phase1(const unsigned int* __restrict__ xw, const unsigned int* __restrict__ eiw,
                       const void* __restrict__ ei, const void* __restrict__ batch,
                       const void* __restrict__ W1, const void* __restrict__ W2,
                       const void* __restrict__ W3, ParamTab tab, int* __restrict__ flags,
                       float* __restrict__ gsumAll, int* __restrict__ Ct,
                       unsigned short* __restrict__ wconv, unsigned short* __restrict__ Wf,
                       int* __restrict__ goff, int* __restrict__ gcnt, int E, int N, int G,
                       int NB, int ntiles, int TILE) {
    __shared__ int h[1024];
    __shared__ int lf0s, lf1s;
    int b = blockIdx.x, t = threadIdx.x;
    if (t == 0) {
        int a0, a1;
        detect_local(xw, eiw, a0, a1);
        lf0s = a0;
        lf1s = a1;
    }
    __syncthreads();
    int lf0 = lf0s, lf1 = lf1s;
    if (b < ntiles) {
        for (int i = t; i < NB; i += 256) h[i] = 0;
        __syncthreads();
        int base = b * TILE;
        for (int i = t; i < TILE; i += 256) {
            int idx = base + i;
            if (idx < E) {
                int d = lf1 ? (int)((const long long*)ei)[(size_t)E + idx]
                            : ((const int*)ei)[(size_t)E + idx];
                atomicAdd(&h[d >> 9], 1);
            }
        }
        __syncthreads();
        for (int k = t; k < NB; k += 256) Ct[k * ntiles + b] = h[k];
    } else if (b < ntiles + 15) {
        int pb = b - ntiles;
        const void* src = tab.p[pb];
        int n = tab.n[pb];
        unsigned short* o = wconv + tab.off[pb];
        if (lf0) {
            const unsigned short* s = (const unsigned short*)src;
            for (int i = t; i < n; i += 256) o[i] = s[i];
        } else {
            const float* s = (const float*)src;
            for (int i = t; i < n; i += 256) o[i] = f2bf(s[i]);
        }
    } else if (b < ntiles + 17) {
        int gi = (b - ntiles - 15) * 256 + t;
        if (gi < G) {
            auto getb = [&](int i) -> int {
                return lf1 ? (int)((const long long*)batch)[i] : ((const int*)batch)[i];
            };
            auto lower = [&](int val) -> int {
                int lo = 0, hi = N;
                while (lo < hi) {
                    int mid = (lo + hi) >> 1;
                    if (getb(mid) < val) lo = mid + 1;
                    else hi = mid;
                }
                return lo;
            };
            int lo = lower(gi), hi = lower(gi + 1);
            goff[gi] = lo;
            gcnt[gi] = hi - lo;
        }
    } else if (b < ntiles + 17 + 24) {
        int idx = (b - ntiles - 17) * 256 + t;  // 0..6143
        int layer = idx >> 11;
        int rem = idx & 2047;
        int kt = rem >> 9;
        int nt = (rem >> 6) & 7;
        int lane = rem & 63;
        const void* W = (layer == 0) ? W1 : ((layer == 1) ? W2 : W3);
        int row = lane & 15, quad = lane >> 4;
        unsigned short* o = Wf + ((size_t)layer * 2048 + (size_t)((kt * 8 + nt) * 64 + lane)) * 8;
#pragma unroll
        for (int j = 0; j < 8; j++) {
            int k = kt * 32 + quad * 8 + j;
            int off = k * HDIM + nt * 16 + row;
            o[j] = lf0 ? ((const unsigned short*)W)[off] : f2bf(((const float*)W)[off]);
        }
    } else {
        for (int i = t; i < 12288; i += 256) gsumAll[i] = 0.f;
        if (t == 0) {
            flags[0] = lf0;
            flags[1] = lf1;
        }
    }
}

// ---------------- per-bucket scan over its tile counts (512 threads; ntiles<=512) ---------
__global__ void s1_scan(int* __restrict__ Ct, int* __restrict__ btot, int NB, int ntiles) {
    __shared__ int buf[512];
    int b = blockIdx.x, t = threadIdx.x;
    int v = (t < ntiles) ? Ct[b * ntiles + t] : 0;
    buf[t] = v;
    __syncthreads();
    for (int o = 1; o < 512; o <<= 1) {
        int a = (t >= o) ? buf[t - o] : 0;
        __syncthreads();
        buf[t] += a;
        __syncthreads();
    }
    if (t < ntiles) Ct[b * ntiles + t] = buf[t] - v;  // exclusive within bucket
    if (t == 0) btot[b] = buf[511];
}

// ---------------- scatter to bucket-contiguous packed pairs ----------------
__global__ void p1_scatter(const void* __restrict__ ei, const int* __restrict__ flags,
                           const int* __restrict__ Ct, const int* __restrict__ btot,
                           unsigned int* __restrict__ pairs, int E, int NB, int ntiles,
                           int TILE) {
    __shared__ int cur[1024];
    __shared__ int bb[256];
    int tile = blockIdx.x, t = threadIdx.x;
    int v = (t < NB) ? btot[t] : 0;
    bb[t] = v;
    __syncthreads();
    for (int o = 1; o < 256; o <<= 1) {
        int a = (t >= o) ? bb[t - o] : 0;
        __syncthreads();
        bb[t] += a;
        __syncthreads();
    }
    if (t < NB) cur[t] = (bb[t] - v) + Ct[t * ntiles + tile];
    __syncthreads();
    int base = tile * TILE;
    bool i64 = flags[1] != 0;
    for (int i = t; i < TILE; i += 256) {
        int idx = base + i;
        if (idx < E) {
            int s, d;
            if (i64) {
                s = (int)((const long long*)ei)[idx];
                d = (int)((const long long*)ei)[(size_t)E + idx];
            } else {
                s = ((const int*)ei)[idx];
                d = ((const int*)ei)[(size_t)E + idx];
            }
            int pos = atomicAdd(&cur[d >> 9], 1);
            pairs[pos] = ((unsigned)(d & 511) << 23) | (unsigned)s;
        }
    }
}

// ---------------- per-bucket: per-node counts -> offs/cnt/dis (csrc no longer built) -----
__global__ void p2_build(const unsigned int* __restrict__ pairs, const int* __restrict__ btot,
                         int* __restrict__ offs, int* __restrict__ cnt,
                         float* __restrict__ dis, int E, int N, int NB) {
    __shared__ int hist[512];
    __shared__ int start[512];
    __shared__ int ps[256];
    __shared__ int bb[256];
    __shared__ int sh_excl[256];
    int b = blockIdx.x, t = threadIdx.x;
    int node0 = b * 512;
    // bucket base via LDS scan of btot
    int v = (t < NB) ? btot[t] : 0;
    bb[t] = v;
    __syncthreads();
    for (int o = 1; o < 256; o <<= 1) {
        int a = (t >= o) ? bb[t - o] : 0;
        __syncthreads();
        bb[t] += a;
        __syncthreads();
    }
    sh_excl[t] = bb[t] - v;
    for (int i = t; i < 512; i += 256) hist[i] = 0;
    __syncthreads();
    int lo = sh_excl[b];
    int hi = lo + ((b < NB) ? btot[b] : 0);
    for (int i = lo + t; i < hi; i += 256) {
        atomicAdd(&hist[pairs[i] >> 23], 1);
    }
    __syncthreads();
    ps[t] = hist[2 * t] + hist[2 * t + 1];
    __syncthreads();
    for (int o = 1; o < 256; o <<= 1) {
        int a = (t >= o) ? ps[t - o] : 0;
        __syncthreads();
        ps[t] += a;
        __syncthreads();
    }
    int e = t ? ps[t - 1] : 0;
    start[2 * t] = e;
    start[2 * t + 1] = e + hist[2 * t];
    __syncthreads();
    for (int i = t; i < 512; i += 256) {
        int node = node0 + i;
        if (node < N) {
            offs[node] = lo + start[i];
            cnt[node] = hist[i];
            dis[node] = rsqrtf((float)(hist[i] + 1));
        }
    }
}

// ---------------- GEMM: C[m,:] = dis[m] * (bnrelu(A)[m,:] @ W), bf16 MFMA ----------------
// Output C in column-block-major layout: element (m, c) at C[((c>>4)*M + m)*16 + (c&15)].
// Non-l0 input A is read in the same blocked layout; l0 reads row-major x.
__global__ __launch_bounds__(256) void mm_mfma(const void* __restrict__ A,
                                               const unsigned short* __restrict__ Wf,
                                               unsigned short* __restrict__ C, int M,
                                               const float* __restrict__ gsumPrev,
                                               const unsigned short* __restrict__ gamma,
                                               const unsigned short* __restrict__ beta,
                                               const float* __restrict__ dis,
                                               const int* __restrict__ flags, int l0mode,
                                               float invn) {
    __shared__ float scs[128], shs[128];
    __shared__ unsigned short ldsC[4 * 16 * 136];
    int t = threadIdx.x;
    if (!l0mode && t < 128) {
        float s = 0.f, s2 = 0.f;
#pragma unroll
        for (int r = 0; r < 16; r++) {
            s += gsumPrev[r * 256 + t];
            s2 += gsumPrev[r * 256 + 128 + t];
        }
        float m = s * invn;
        float vv = s2 * invn - m * m;
        float sc = bf2f(gamma[t]) * rsqrtf(vv + 1e-5f);
        scs[t] = sc;
        shs[t] = bf2f(beta[t]) - m * sc;
    }
    __syncthreads();
    int gid = blockIdx.x * blockDim.x + t;
    int wave = gid >> 6;
    int lane = t & 63;
    int wv = t >> 6;
    int m0 = wave * 16;
    if (m0 >= M) return;
    int row = lane & 15, quad = lane >> 4;
    bool xfp32 = l0mode && !flags[0];
    const unsigned short* arow = (const unsigned short*)A + (size_t)(m0 + row) * HDIM + quad * 8;
    const float* arowf = (const float*)A + (size_t)(m0 + row) * HDIM + quad * 8;
    const unsigned short* ablk = (const unsigned short*)A;
    fx4 acc[8];
#pragma unroll
    for (int k = 0; k < 8; k++) acc[k] = (fx4){0.f, 0.f, 0.f, 0.f};
#pragma unroll
    for (int kt = 0; kt < 4; kt++) {
        bf16x8 a;
        if (xfp32) {
            fx4 f0 = *(const fx4*)(arowf + kt * 32);
            fx4 f1 = *(const fx4*)(arowf + kt * 32 + 4);
            usx8 tt;
#pragma unroll
            for (int q = 0; q < 4; q++) tt[q] = f2bf(f0[q]);
#pragma unroll
            for (int q = 0; q < 4; q++) tt[4 + q] = f2bf(f1[q]);
            a = __builtin_bit_cast(bf16x8, tt);
        } else if (l0mode) {
            usx8 raw = *(const usx8*)(arow + kt * 32);
            a = __builtin_bit_cast(bf16x8, raw);
        } else {
            // blocked-layout read: col c0 = kt*32 + quad*8 (8 contiguous within a 16-col slice)
            int c0 = kt * 32 + quad * 8;
            usx8 raw =
                *(const usx8*)(ablk + ((size_t)(c0 >> 4) * M + (m0 + row)) * 16 + (c0 & 15));
            fx4 s0 = *(const fx4*)&scs[c0];
            fx4 s1 = *(const fx4*)&scs[c0 + 4];
            fx4 h0 = *(const fx4*)&shs[c0];
            fx4 h1 = *(const fx4*)&shs[c0 + 4];
            usx8 tt;
#pragma unroll
            for (int q = 0; q < 4; q++)
                tt[q] = f2bf(fmaxf(s0[q] * bf2f(raw[q]) + h0[q], 0.f));
#pragma unroll
            for (int q = 0; q < 4; q++)
                tt[4 + q] = f2bf(fmaxf(s1[q] * bf2f(raw[4 + q]) + h1[q], 0.f));
            a = __builtin_bit_cast(bf16x8, tt);
        }
        const unsigned short* wf = Wf + ((size_t)(kt * 8) * 64 + lane) * 8;
#pragma unroll
        for (int nt = 0; nt < 8; nt++) {
            bf16x8 bfr = __builtin_bit_cast(bf16x8, *(const usx8*)(wf + (size_t)nt * 64 * 8));
            acc[nt] = __builtin_amdgcn_mfma_f32_16x16x32_bf16(a, bfr, acc[nt], 0, 0, 0);
        }
    }
    float dsc[4];
#pragma unroll
    for (int r = 0; r < 4; r++) dsc[r] = dis[m0 + quad * 4 + r];
    // transpose through per-wave LDS region (stride 136 shorts, 16B-aligned rows)
    unsigned short* lw = ldsC + wv * 16 * 136;
#pragma unroll
    for (int nt = 0; nt < 8; nt++) {
        int col = nt * 16 + row;
#pragma unroll
        for (int r = 0; r < 4; r++) {
            lw[(quad * 4 + r) * 136 + col] = f2bf(acc[nt][r] * dsc[r]);
        }
    }
    // no __syncthreads needed: same-wave LDS RAW handled by lgkmcnt
    // write out in column-block-major layout: lane -> (cbw, sub8); 4 chunks each
    int sub8 = lane & 7, cbw = lane >> 3;
#pragma unroll
    for (int k = 0; k < 4; k++) {
        int ci = k * 8 + sub8;
        int nd = ci >> 1, half = ci & 1;
        if (m0 + nd < M) {
            const unsigned short* src = lw + nd * 136 + cbw * 16 + half * 8;
            unsigned short* dst = C + ((size_t)cbw * M + (m0 + nd)) * 16 + half * 8;
            *(usx8*)dst = *(const usx8*)src;
        }
    }
}

// ---------------- aggregation v2: bucket-pair streaming + LDS scatter-accumulate ---------
// Block = (dest bucket of 512 nodes) x (16-col slice cb = blockIdx&7 -> per-XCD L2-resident
// hw slice, 3.2MB). The bucket's pairs range is streamed LINEARLY (coalesced, no per-node
// index walk, no divergence); each pair's gathered 16B fragment is scattered into a 32KB
// LDS accumulator via ds_add_f32 (XOR bank swizzle col^(l&15)). Self row initializes the
// accumulator; finalize = dis-scale + bias + stats + nontemporal store.
__global__ __launch_bounds__(256) void aggregate(
    const unsigned short* __restrict__ hw, const float* __restrict__ dis,
    const int* __restrict__ offs, const int* __restrict__ btot,
    const unsigned int* __restrict__ pairs, const unsigned short* __restrict__ bias,
    unsigned short* __restrict__ agg, float* __restrict__ gsum16, int n) {
    __shared__ float accum[8192];  // [512][16] swizzled; reused for stat reduction
    int t = threadIdx.x;
    int cb = blockIdx.x & 7;
    int bucket = blockIdx.x >> 3;
    int node0 = bucket * 512;
    const unsigned short* hslice = hw + (size_t)cb * n * 16;
    unsigned short* aslice = agg + (size_t)cb * n * 16;
    // self-init accum from hw rows (rows are dis[src]-prescaled by mm_mfma)
    for (int i = t; i < 512; i += 256) {
        int node = node0 + i;
        int sw = i & 15;
        if (node < n) {
            usx8 r0 = *(const usx8*)(hslice + (size_t)node * 16);
            usx8 r1 = *(const usx8*)(hslice + (size_t)node * 16 + 8);
#pragma unroll
            for (int q = 0; q < 8; q++) accum[i * 16 + (q ^ sw)] = bf2f(r0[q]);
#pragma unroll
            for (int q = 0; q < 8; q++) accum[i * 16 + ((8 + q) ^ sw)] = bf2f(r1[q]);
        }
    }
    __syncthreads();
    int lo = offs[node0];  // bucket base (start[0]==0)
    int hi = lo + btot[bucket];
    int colOff = (t & 1) * 8;
    // stream pairs: 2 lanes per pair, 128 pairs per block-iteration, unroll 2 for MLP
    int p = lo + (t >> 1);
    for (; p + 128 < hi; p += 256) {
        unsigned pr0 = pairs[p];
        unsigned pr1 = pairs[p + 128];
        int l0 = pr0 >> 23, s0 = pr0 & 0x7fffff;
        int l1 = pr1 >> 23, s1 = pr1 & 0x7fffff;
        usx8 v0 = *(const usx8*)(hslice + (size_t)s0 * 16 + colOff);
        usx8 v1 = *(const usx8*)(hslice + (size_t)s1 * 16 + colOff);
        int sw0 = l0 & 15, sw1 = l1 & 15;
#pragma unroll
        for (int q = 0; q < 8; q++)
            atomicAdd(&accum[l0 * 16 + ((colOff + q) ^ sw0)], bf2f(v0[q]));
#pragma unroll
        for (int q = 0; q < 8; q++)
            atomicAdd(&accum[l1 * 16 + ((colOff + q) ^ sw1)], bf2f(v1[q]));
    }
    if (p < hi) {
        unsigned pr0 = pairs[p];
        int l0 = pr0 >> 23, s0 = pr0 & 0x7fffff;
        usx8 v0 = *(const usx8*)(hslice + (size_t)s0 * 16 + colOff);
        int sw0 = l0 & 15;
#pragma unroll
        for (int q = 0; q < 8; q++)
            atomicAdd(&accum[l0 * 16 + ((colOff + q) ^ sw0)], bf2f(v0[q]));
    }
    __syncthreads();
    // finalize: val = bias + dis[dest] * acc; stats on stored bf16 value
    usx8 bv0 = *(const usx8*)(bias + cb * 16);
    usx8 bv1 = *(const usx8*)(bias + cb * 16 + 8);
    float csum[16], csq[16];
#pragma unroll
    for (int q = 0; q < 16; q++) {
        csum[q] = 0.f;
        csq[q] = 0.f;
    }
#pragma unroll
    for (int pass = 0; pass < 2; pass++) {
        int i = pass * 256 + t;
        int node = node0 + i;
        if (node < n) {
            float di = dis[node];
            int sw = i & 15;
            usx8 o0, o1;
#pragma unroll
            for (int q = 0; q < 8; q++) {
                float val = bf2f(bv0[q]) + di * accum[i * 16 + (q ^ sw)];
                o0[q] = f2bf(val);
                float vr = bf2f(o0[q]);
                csum[q] += vr;
                csq[q] += vr * vr;
            }
#pragma unroll
            for (int q = 0; q < 8; q++) {
                float val = bf2f(bv1[q]) + di * accum[i * 16 + ((8 + q) ^ sw)];
                o1[q] = f2bf(val);
                float vr = bf2f(o1[q]);
                csum[8 + q] += vr;
                csq[8 + q] += vr * vr;
            }
            __builtin_nontemporal_store(o0, (usx8*)(aslice + (size_t)node * 16));
            __builtin_nontemporal_store(o1, (usx8*)(aslice + (size_t)node * 16 + 8));
        }
    }
    __syncthreads();
    int rep = (bucket & 15) * 256;
#pragma unroll
    for (int q = 0; q < 16; q++) accum[t * 16 + q] = csum[q];
    __syncthreads();
    for (int s = 128; s >= 1; s >>= 1) {
        if (t < s) {
#pragma unroll
            for (int q = 0; q < 16; q++) accum[t * 16 + q] += accum[(t + s) * 16 + q];
        }
        __syncthreads();
    }
    if (t < 16) atomicAdd(&gsum16[rep + cb * 16 + t], accum[t]);
    __syncthreads();
#pragma unroll
    for (int q = 0; q < 16; q++) accum[t * 16 + q] = csq[q];
    __syncthreads();
    for (int s = 128; s >= 1; s >>= 1) {
        if (t < s) {
#pragma unroll
            for (int q = 0; q < 16; q++) accum[t * 16 + q] += accum[(t + s) * 16 + q];
        }
        __syncthreads();
    }
    if (t < 16) atomicAdd(&gsum16[rep + 128 + cb * 16 + t], accum[t]);
}

// ---------------- pooling (computes BN3 in-block, fused ReLU; blocked input) -------------
__global__ void pool(const unsigned short* __restrict__ hin, const int* __restrict__ goff,
                     const int* __restrict__ gcnt, const float* __restrict__ gsum3,
                     const unsigned short* __restrict__ gamma,
                     const unsigned short* __restrict__ beta, float* __restrict__ pooled,
                     float invn, int N_) {
    __shared__ float scs[128], shs[128];
    __shared__ float ls[256];
    int g = blockIdx.x, t = threadIdx.x;
    if (t < 128) {
        float s = 0.f, s2 = 0.f;
#pragma unroll
        for (int r = 0; r < 16; r++) {
            s += gsum3[r * 256 + t];
            s2 += gsum3[r * 256 + 128 + t];
        }
        float m = s * invn;
        float vv = s2 * invn - m * m;
        float sc = bf2f(gamma[t]) * rsqrtf(vv + 1e-5f);
        scs[t] = sc;
        shs[t] = bf2f(beta[t]) - m * sc;
    }
    __syncthreads();
    int c = t & 127, p = t >> 7;
    float scale = scs[c], shift = shs[c];
    int s = goff[g], cn = gcnt[g];
    const unsigned short* base = hin + (size_t)(c >> 4) * N_ * 16 + (c & 15);
    float acc = 0.f;
    for (int r = s + p; r < s + cn; r += 2)
        acc += fmaxf(scale * bf2f(base[(size_t)r * 16]) + shift, 0.f);
    ls[t] = acc;
    __syncthreads();
    if (t < 128) pooled[(size_t)g * HDIM + t] = (ls[t] + ls[t + 128]) / fmaxf((float)cn, 1.f);
}
__global__ void pooled_bn(const float* __restrict__ pooled, const unsigned short* __restrict__ g,
                          const unsigned short* __restrict__ be, float* __restrict__ psc,
                          float* __restrict__ psh, int G_) {
    int t = threadIdx.x;
    int c = t & 127, p = t >> 7;
    float s = 0.f, s2 = 0.f;
    for (int r = p; r < G_; r += 4) {
        float v = pooled[(size_t)r * HDIM + c];
        s += v;
        s2 += v * v;
    }
    __shared__ float ls[512], ls2[512];
    ls[t] = s;
    ls2[t] = s2;
    __syncthreads();
    if (t < 128) {
        float S = ls[t] + ls[t + 128] + ls[t + 256] + ls[t + 384];
        float S2 = ls2[t] + ls2[t + 128] + ls2[t + 256] + ls2[t + 384];
        float m = S / (float)G_;
        float v = S2 / (float)G_ - m * m;
        float sc = bf2f(g[t]) * rsqrtf(v + 1e-5f);
        psc[t] = sc;
        psh[t] = bf2f(be[t]) - m * sc;
    }
}
// ---------------- fused MLP head + log_softmax ----------------
__global__ void mlp12(const float* __restrict__ pooled, const float* __restrict__ psc,
                      const float* __restrict__ psh, const unsigned short* __restrict__ lw1,
                      const unsigned short* __restrict__ lb1,
                      const unsigned short* __restrict__ lw2,
                      const unsigned short* __restrict__ lb2, void* __restrict__ out,
                      const int* __restrict__ flags) {
    int r = blockIdx.x, t = threadIdx.x;
    __shared__ float row[128];
    __shared__ float z1s[128];
    __shared__ float z2[10];
    __shared__ float lse;
    row[t] = psc[t] * pooled[(size_t)r * HDIM + t] + psh[t];
    __syncthreads();
    float acc = bf2f(lb1[t]);
    for (int k = 0; k < 128; k++) acc += row[k] * bf2f(lw1[k * HDIM + t]);
    z1s[t] = fmaxf(acc, 0.f);
    __syncthreads();
    if (t < 10) {
        float a = bf2f(lb2[t]);
        for (int k = 0; k < 128; k++) a += z1s[k] * bf2f(lw2[k * 10 + t]);
        z2[t] = a;
    }
    __syncthreads();
    if (t == 0) {
        float m = z2[0];
        for (int j = 1; j < 10; j++) m = fmaxf(m, z2[j]);
        float s = 0.f;
        for (int j = 0; j < 10; j++) s += expf(z2[j] - m);
        lse = m + logf(s);
    }
    __syncthreads();
    if (t < 10) {
        float v = z2[t] - lse;
        if (flags[0]) ((unsigned short*)out)[r * 10 + t] = f2bf(v);
        else ((float*)out)[r * 10 + t] = v;
    }
}

extern "C" void kernel_launch(void* const* d_in, const int* in_sizes, int n_in,
                              void* d_out, int out_size, void* d_ws, size_t ws_size,
                              hipStream_t stream) {
    const void* x = d_in[0];
    const void* ei = d_in[1];
    const void* batch = d_in[2];

    int N_ = in_sizes[2];
    int E_ = in_sizes[1] / 2;
    int G_ = out_size / 10;

    const int TILE = 4096;  // ntiles <= 512 required by s1_scan (E<=2M)
    int NB = (N_ + 511) / 512;  // <=256 required by in-kernel base scans
    int ntiles = (E_ + TILE - 1) / TILE;
    int L = NB * ntiles;

    char* ws = (char*)d_ws;
    auto alloc = [&](size_t bytes) -> char* {
        char* p = ws;
        ws += (bytes + 255) & ~(size_t)255;
        return p;
    };
    int* flags = (int*)alloc(256);
    float* dis = (float*)alloc((size_t)N_ * 4);
    int* offs = (int*)alloc((size_t)N_ * 4);
    int* cnt = (int*)alloc((size_t)N_ * 4);
    int* Ct = (int*)alloc((size_t)L * 4);
    int* btot = (int*)alloc(1024);
    unsigned int* pairs = (unsigned int*)alloc((size_t)E_ * 4);
    unsigned short* hw = (unsigned short*)alloc((size_t)N_ * HDIM * 2);
    unsigned short* aggbuf = (unsigned short*)alloc((size_t)N_ * HDIM * 2);
    unsigned short* wconv = (unsigned short*)alloc(70000 * 2);
    unsigned short* wfrag = (unsigned short*)alloc(3 * HDIM * HDIM * 2);
    float* gsumAll = (float*)alloc(12288 * 4);  // 3 layers x 16 replicas x (128 sum + 128 sq)
    int* gcnt = (int*)alloc((size_t)G_ * 4);
    int* goff = (int*)alloc((size_t)G_ * 4);
    float* pooled = (float*)alloc((size_t)G_ * HDIM * 4);
    float* psc = (float*)alloc(128 * 4);
    float* psh = (float*)alloc(128 * 4);

    // wconv layout (element offsets)
    const int oB = 49152;
    const int oLB1 = oB + 1408;
    const int oLW1 = oLB1 + 128;
    const int oLW2 = oLW1 + 16384;
    const int oLB2 = oLW2 + 1280;

    ParamTab tab;
    const int srcIdx[15] = {4, 5, 6, 8, 9, 10, 12, 13, 14, 15, 16, 18, 17, 19, 20};
    const int dstOff[15] = {oB + 0, oB + 128, oB + 256,
                            oB + 384, oB + 512, oB + 640,
                            oB + 768, oB + 896, oB + 1024,
                            oB + 1152, oB + 1280,
                            oLB1, oLW1, oLW2, oLB2};
    for (int i = 0; i < 15; i++) {
        tab.p[i] = d_in[srcIdx[i]];
        tab.n[i] = in_sizes[srcIdx[i]];
        tab.off[i] = dstOff[i];
    }

    int p1_grid = ntiles + 15 + 2 + 24 + 1;
    phase1<<<p1_grid, 256, 0, stream>>>((const unsigned int*)x, (const unsigned int*)ei, ei,
                                        batch, d_in[3], d_in[7], d_in[11], tab, flags, gsumAll,
                                        Ct, wconv, wfrag, goff, gcnt, E_, N_, G_, NB, ntiles,
                                        TILE);
    s1_scan<<<NB, 512, 0, stream>>>(Ct, btot, NB, ntiles);
    p1_scatter<<<ntiles, 256, 0, stream>>>(ei, flags, Ct, btot, pairs, E_, NB, ntiles, TILE);
    p2_build<<<NB, 256, 0, stream>>>(pairs, btot, offs, cnt, dis, E_, N_, NB);

    int mm_blocks = (((N_ + 15) / 16) * 64 + 255) / 256;
    float invn = 1.f / (float)N_;

    for (int l = 0; l < 3; l++) {
        const void* A = (l == 0) ? x : (const void*)aggbuf;
        const float* gp = (l == 0) ? nullptr : (gsumAll + (size_t)(l - 1) * 4096);
        const unsigned short* gam = wconv + oB + (l ? (l - 1) * 384 + 128 : 0);
        const unsigned short* bet = wconv + oB + (l ? (l - 1) * 384 + 256 : 0);
        mm_mfma<<<mm_blocks, 256, 0, stream>>>(A, wfrag + (size_t)l * HDIM * HDIM, hw, N_, gp,
                                               gam, bet, dis, flags, (l == 0) ? 1 : 0, invn);
        aggregate<<<NB * 8, 256, 0, stream>>>(hw, dis, offs, btot, pairs,
                                              wconv + oB + l * 384, aggbuf,
                                              gsumAll + (size_t)l * 4096, N_);
    }

    pool<<<G_, 256, 0, stream>>>(aggbuf, goff, gcnt, gsumAll + 2 * 4096,
                                 wconv + oB + 2 * 384 + 128, wconv + oB + 2 * 384 + 256, pooled,
                                 invn, N_);
    pooled_bn<<<1, 512, 0, stream>>>(pooled, wconv + oB + 1152, wconv + oB + 1280, psc, psh, G_);
    mlp12<<<G_, 128, 0, stream>>>(pooled, psc, psh, wconv + oLW1, wconv + oLB1, wconv + oLW2,
                                  wconv + oLB2, d_out, flags);
}

// Round 6
// 517.187 us; speedup vs baseline: 7.4322x; 7.4322x over previous
//
#include <hip/hip_runtime.h>
#include <hip/hip_bf16.h>
#include <cstdint>

#define HDIM 128

typedef __bf16 bf16x8 __attribute__((ext_vector_type(8)));
typedef unsigned short usx8 __attribute__((ext_vector_type(8)));
typedef float fx4 __attribute__((ext_vector_type(4)));

__device__ __forceinline__ float bf2f(unsigned short u) {
    unsigned int x = ((unsigned int)u) << 16;
    return __uint_as_float(x);
}
__device__ __forceinline__ unsigned short f2bf(float f) {
    unsigned int x = __float_as_uint(f);
    x += 0x7fffu + ((x >> 16) & 1u);
    return (unsigned short)(x >> 16);
}

__device__ __forceinline__ void detect_local(const unsigned int* xw, const unsigned int* eiw,
                                             int& f0, int& f1) {
    int sane = 0;
    for (int k = 0; k < 64; k++) {
        unsigned int w = xw[k];
        unsigned short ss[2] = {(unsigned short)(w & 0xffffu), (unsigned short)(w >> 16)};
        for (int q = 0; q < 2; q++) {
            int e = (ss[q] >> 7) & 0xFF;
            if ((ss[q] & 0x7fffu) == 0 || (e >= 100 && e <= 140)) sane++;
        }
    }
    f0 = (sane >= 110) ? 1 : 0;
    int zeros = 0;
    for (int k = 1; k < 64; k += 2)
        if (eiw[k] == 0) zeros++;
    f1 = (zeros >= 24) ? 1 : 0;
}

struct ParamTab {
    const void* p[15];
    int n[15];
    int off[15];
};

// ---------------- phase1: hist + param-convert + gbounds + repack + init ----------------
__global__ void phase1(const unsigned int* __restrict__ xw, const unsigned int* __restrict__ eiw,
                       const void* __restrict__ ei, const void* __restrict__ batch,
                       const void* __restrict__ W1, const void* __restrict__ W2,
                       const void* __restrict__ W3, ParamTab tab, int* __restrict__ flags,
                       float* __restrict__ gsumAll, int* __restrict__ Ct,
                       unsigned short* __restrict__ wconv, unsigned short* __restrict__ Wf,
                       int* __restrict__ goff, int* __restrict__ gcnt, int E, int N, int G,
                       int NB, int ntiles, int TILE) {
    __shared__ int h[1024];
    __shared__ int lf0s, lf1s;
    int b = blockIdx.x, t = threadIdx.x;
    if (t == 0) {
        int a0, a1;
        detect_local(xw, eiw, a0, a1);
        lf0s = a0;
        lf1s = a1;
    }
    __syncthreads();
    int lf0 = lf0s, lf1 = lf1s;
    if (b < ntiles) {
        for (int i = t; i < NB; i += 256) h[i] = 0;
        __syncthreads();
        int base = b * TILE;
        for (int i = t; i < TILE; i += 256) {
            int idx = base + i;
            if (idx < E) {
                int d = lf1 ? (int)((const long long*)ei)[(size_t)E + idx]
                            : ((const int*)ei)[(size_t)E + idx];
                atomicAdd(&h[d >> 9], 1);
            }
        }
        __syncthreads();
        for (int k = t; k < NB; k += 256) Ct[k * ntiles + b] = h[k];
    } else if (b < ntiles + 15) {
        int pb = b - ntiles;
        const void* src = tab.p[pb];
        int n = tab.n[pb];
        unsigned short* o = wconv + tab.off[pb];
        if (lf0) {
            const unsigned short* s = (const unsigned short*)src;
            for (int i = t; i < n; i += 256) o[i] = s[i];
        } else {
            const float* s = (const float*)src;
            for (int i = t; i < n; i += 256) o[i] = f2bf(s[i]);
        }
    } else if (b < ntiles + 17) {
        int gi = (b - ntiles - 15) * 256 + t;
        if (gi < G) {
            auto getb = [&](int i) -> int {
                return lf1 ? (int)((const long long*)batch)[i] : ((const int*)batch)[i];
            };
            auto lower = [&](int val) -> int {
                int lo = 0, hi = N;
                while (lo < hi) {
                    int mid = (lo + hi) >> 1;
                    if (getb(mid) < val) lo = mid + 1;
                    else hi = mid;
                }
                return lo;
            };
            int lo = lower(gi), hi = lower(gi + 1);
            goff[gi] = lo;
            gcnt[gi] = hi - lo;
        }
    } else if (b < ntiles + 17 + 24) {
        int idx = (b - ntiles - 17) * 256 + t;  // 0..6143
        int layer = idx >> 11;
        int rem = idx & 2047;
        int kt = rem >> 9;
        int nt = (rem >> 6) & 7;
        int lane = rem & 63;
        const void* W = (layer == 0) ? W1 : ((layer == 1) ? W2 : W3);
        int row = lane & 15, quad = lane >> 4;
        unsigned short* o = Wf + ((size_t)layer * 2048 + (size_t)((kt * 8 + nt) * 64 + lane)) * 8;
#pragma unroll
        for (int j = 0; j < 8; j++) {
            int k = kt * 32 + quad * 8 + j;
            int off = k * HDIM + nt * 16 + row;
            o[j] = lf0 ? ((const unsigned short*)W)[off] : f2bf(((const float*)W)[off]);
        }
    } else {
        for (int i = t; i < 6144; i += 256) gsumAll[i] = 0.f;
        if (t == 0) {
            flags[0] = lf0;
            flags[1] = lf1;
        }
    }
}

// ---------------- per-bucket scan over its tile counts (512 threads; ntiles<=512) ---------
__global__ void s1_scan(int* __restrict__ Ct, int* __restrict__ btot, int NB, int ntiles) {
    __shared__ int buf[512];
    int b = blockIdx.x, t = threadIdx.x;
    int v = (t < ntiles) ? Ct[b * ntiles + t] : 0;
    buf[t] = v;
    __syncthreads();
    for (int o = 1; o < 512; o <<= 1) {
        int a = (t >= o) ? buf[t - o] : 0;
        __syncthreads();
        buf[t] += a;
        __syncthreads();
    }
    if (t < ntiles) Ct[b * ntiles + t] = buf[t] - v;  // exclusive within bucket
    if (t == 0) btot[b] = buf[511];
}

// ---------------- scatter to bucket-contiguous packed pairs ----------------
__global__ void p1_scatter(const void* __restrict__ ei, const int* __restrict__ flags,
                           const int* __restrict__ Ct, const int* __restrict__ btot,
                           unsigned int* __restrict__ pairs, int E, int NB, int ntiles,
                           int TILE) {
    __shared__ int cur[1024];
    __shared__ int bb[256];
    int tile = blockIdx.x, t = threadIdx.x;
    int v = (t < NB) ? btot[t] : 0;
    bb[t] = v;
    __syncthreads();
    for (int o = 1; o < 256; o <<= 1) {
        int a = (t >= o) ? bb[t - o] : 0;
        __syncthreads();
        bb[t] += a;
        __syncthreads();
    }
    if (t < NB) cur[t] = (bb[t] - v) + Ct[t * ntiles + tile];
    __syncthreads();
    int base = tile * TILE;
    bool i64 = flags[1] != 0;
    for (int i = t; i < TILE; i += 256) {
        int idx = base + i;
        if (idx < E) {
            int s, d;
            if (i64) {
                s = (int)((const long long*)ei)[idx];
                d = (int)((const long long*)ei)[(size_t)E + idx];
            } else {
                s = ((const int*)ei)[idx];
                d = ((const int*)ei)[(size_t)E + idx];
            }
            int pos = atomicAdd(&cur[d >> 9], 1);
            pairs[pos] = ((unsigned)(d & 511) << 23) | (unsigned)s;
        }
    }
}

// ---------------- per-bucket: group by node, emit csrc/offs/cnt/dis ----------------
__global__ void p2_build(const unsigned int* __restrict__ pairs, const int* __restrict__ btot,
                         int* __restrict__ csrc, int* __restrict__ offs, int* __restrict__ cnt,
                         float* __restrict__ dis, int E, int N, int NB) {
    __shared__ int hist[512];
    __shared__ int start[512];
    __shared__ int cur[512];
    __shared__ int ps[256];
    __shared__ int bb[256];
    __shared__ int sh_excl[256];
    int b = blockIdx.x, t = threadIdx.x;
    int node0 = b * 512;
    // bucket base via LDS scan of btot
    int v = (t < NB) ? btot[t] : 0;
    bb[t] = v;
    __syncthreads();
    for (int o = 1; o < 256; o <<= 1) {
        int a = (t >= o) ? bb[t - o] : 0;
        __syncthreads();
        bb[t] += a;
        __syncthreads();
    }
    sh_excl[t] = bb[t] - v;
    for (int i = t; i < 512; i += 256) hist[i] = 0;
    __syncthreads();
    int lo = sh_excl[b];
    int hi = lo + ((b < NB) ? btot[b] : 0);
    for (int i = lo + t; i < hi; i += 256) {
        atomicAdd(&hist[pairs[i] >> 23], 1);
    }
    __syncthreads();
    ps[t] = hist[2 * t] + hist[2 * t + 1];
    __syncthreads();
    for (int o = 1; o < 256; o <<= 1) {
        int a = (t >= o) ? ps[t - o] : 0;
        __syncthreads();
        ps[t] += a;
        __syncthreads();
    }
    int e = t ? ps[t - 1] : 0;
    start[2 * t] = e;
    start[2 * t + 1] = e + hist[2 * t];
    __syncthreads();
    for (int i = t; i < 512; i += 256) {
        cur[i] = 0;
        int node = node0 + i;
        if (node < N) {
            offs[node] = lo + start[i];
            cnt[node] = hist[i];
            dis[node] = rsqrtf((float)(hist[i] + 1));
        }
    }
    __syncthreads();
    for (int i = lo + t; i < hi; i += 256) {
        unsigned int p = pairs[i];
        int l = p >> 23;
        int pos = lo + start[l] + atomicAdd(&cur[l], 1);
        csrc[pos] = (int)(p & 0x7fffffu);
    }
}

// ---------------- GEMM: C[m,:] = dis[m] * (bnrelu(A)[m,:] @ W), bf16 MFMA ----------------
// gsumPrev: 8-replica sums for input BN (null for layer 0)
__global__ __launch_bounds__(256) void mm_mfma(const void* __restrict__ A,
                                               const unsigned short* __restrict__ Wf,
                                               unsigned short* __restrict__ C, int M,
                                               const float* __restrict__ gsumPrev,
                                               const unsigned short* __restrict__ gamma,
                                               const unsigned short* __restrict__ beta,
                                               const float* __restrict__ dis,
                                               const int* __restrict__ flags, int l0mode,
                                               float invn) {
    __shared__ float scs[128], shs[128];
    __shared__ unsigned short ldsC[4 * 16 * 136];
    int t = threadIdx.x;
    if (!l0mode && t < 128) {
        float s = 0.f, s2 = 0.f;
#pragma unroll
        for (int r = 0; r < 8; r++) {
            s += gsumPrev[r * 256 + t];
            s2 += gsumPrev[r * 256 + 128 + t];
        }
        float m = s * invn;
        float vv = s2 * invn - m * m;
        float sc = bf2f(gamma[t]) * rsqrtf(vv + 1e-5f);
        scs[t] = sc;
        shs[t] = bf2f(beta[t]) - m * sc;
    }
    __syncthreads();
    int gid = blockIdx.x * blockDim.x + t;
    int wave = gid >> 6;
    int lane = t & 63;
    int wv = t >> 6;
    int m0 = wave * 16;
    if (m0 >= M) return;
    int row = lane & 15, quad = lane >> 4;
    bool xfp32 = l0mode && !flags[0];
    const unsigned short* arow = (const unsigned short*)A + (size_t)(m0 + row) * HDIM + quad * 8;
    const float* arowf = (const float*)A + (size_t)(m0 + row) * HDIM + quad * 8;
    fx4 acc[8];
#pragma unroll
    for (int k = 0; k < 8; k++) acc[k] = (fx4){0.f, 0.f, 0.f, 0.f};
#pragma unroll
    for (int kt = 0; kt < 4; kt++) {
        bf16x8 a;
        if (xfp32) {
            fx4 f0 = *(const fx4*)(arowf + kt * 32);
            fx4 f1 = *(const fx4*)(arowf + kt * 32 + 4);
            usx8 tt;
#pragma unroll
            for (int q = 0; q < 4; q++) tt[q] = f2bf(f0[q]);
#pragma unroll
            for (int q = 0; q < 4; q++) tt[4 + q] = f2bf(f1[q]);
            a = __builtin_bit_cast(bf16x8, tt);
        } else {
            usx8 raw = *(const usx8*)(arow + kt * 32);
            if (!l0mode) {
                int col = kt * 32 + quad * 8;
                fx4 s0 = *(const fx4*)&scs[col];
                fx4 s1 = *(const fx4*)&scs[col + 4];
                fx4 h0 = *(const fx4*)&shs[col];
                fx4 h1 = *(const fx4*)&shs[col + 4];
                usx8 tt;
#pragma unroll
                for (int q = 0; q < 4; q++)
                    tt[q] = f2bf(fmaxf(s0[q] * bf2f(raw[q]) + h0[q], 0.f));
#pragma unroll
                for (int q = 0; q < 4; q++)
                    tt[4 + q] = f2bf(fmaxf(s1[q] * bf2f(raw[4 + q]) + h1[q], 0.f));
                a = __builtin_bit_cast(bf16x8, tt);
            } else {
                a = __builtin_bit_cast(bf16x8, raw);
            }
        }
        const unsigned short* wf = Wf + ((size_t)(kt * 8) * 64 + lane) * 8;
#pragma unroll
        for (int nt = 0; nt < 8; nt++) {
            bf16x8 bfr = __builtin_bit_cast(bf16x8, *(const usx8*)(wf + (size_t)nt * 64 * 8));
            acc[nt] = __builtin_amdgcn_mfma_f32_16x16x32_bf16(a, bfr, acc[nt], 0, 0, 0);
        }
    }
    float dsc[4];
#pragma unroll
    for (int r = 0; r < 4; r++) dsc[r] = dis[m0 + quad * 4 + r];
    // transpose through per-wave LDS region (stride 136 shorts, 16B-aligned rows)
    unsigned short* lw = ldsC + wv * 16 * 136;
#pragma unroll
    for (int nt = 0; nt < 8; nt++) {
        int col = nt * 16 + row;
#pragma unroll
        for (int r = 0; r < 4; r++) {
            lw[(quad * 4 + r) * 136 + col] = f2bf(acc[nt][r] * dsc[r]);
        }
    }
    // no __syncthreads needed: same-wave LDS RAW handled by lgkmcnt
    int row16 = lane >> 2;
    int seg = lane & 3;
    const unsigned short* src = lw + row16 * 136 + seg * 32;
    unsigned short* dst = C + (size_t)(m0 + row16) * HDIM + seg * 32;
#pragma unroll
    for (int k = 0; k < 4; k++) {
        *(usx8*)(dst + k * 8) = *(const usx8*)(src + k * 8);
    }
}

// ---------------- aggregation (persistent) + fused BN col-stats ----------------
__global__ __launch_bounds__(256) void aggregate(const unsigned short* __restrict__ hw,
                                                 const float* __restrict__ dis,
                                                 const int* __restrict__ offs,
                                                 const int* __restrict__ cnt,
                                                 const int* __restrict__ csrc,
                                                 const unsigned short* __restrict__ bias,
                                                 unsigned short* __restrict__ agg,
                                                 float* __restrict__ gsum8, int n) {
    __shared__ float red[16 * 128];
    int t = threadIdx.x;
    int lane = t & 63;
    int wv = t >> 6;
    int grp = lane >> 4, sub = lane & 15;
    int colb = sub * 8;
    usx8 bv = *(const usx8*)(bias + colb);
    float csum[8], csq[8];
#pragma unroll
    for (int q = 0; q < 8; q++) {
        csum[q] = 0.f;
        csq[q] = 0.f;
    }
    int stride = gridDim.x * 16;
    for (int node = blockIdx.x * 16 + wv * 4 + grp; node < n; node += stride) {
        usx8 sv = *(const usx8*)(hw + (size_t)node * HDIM + colb);
        float a[8];
#pragma unroll
        for (int q = 0; q < 8; q++) a[q] = bf2f(sv[q]);
        int o = offs[node], c = cnt[node];
        int s0 = (c > 0) ? csrc[o] : 0;
        int s1 = (c > 1) ? csrc[o + 1] : 0;
        int s2 = (c > 2) ? csrc[o + 2] : 0;
        int s3 = (c > 3) ? csrc[o + 3] : 0;
        int j = 0;
        while (j < c) {
            usx8 v0 = *(const usx8*)(hw + (size_t)s0 * HDIM + colb);
            usx8 v1 = *(const usx8*)(hw + (size_t)s1 * HDIM + colb);
            usx8 v2 = *(const usx8*)(hw + (size_t)s2 * HDIM + colb);
            usx8 v3 = *(const usx8*)(hw + (size_t)s3 * HDIM + colb);
            s0 = (j + 4 < c) ? csrc[o + j + 4] : 0;
            s1 = (j + 5 < c) ? csrc[o + j + 5] : 0;
            s2 = (j + 6 < c) ? csrc[o + j + 6] : 0;
            s3 = (j + 7 < c) ? csrc[o + j + 7] : 0;
#pragma unroll
            for (int q = 0; q < 8; q++) a[q] += bf2f(v0[q]);
            if (j + 1 < c) {
#pragma unroll
                for (int q = 0; q < 8; q++) a[q] += bf2f(v1[q]);
            }
            if (j + 2 < c) {
#pragma unroll
                for (int q = 0; q < 8; q++) a[q] += bf2f(v2[q]);
            }
            if (j + 3 < c) {
#pragma unroll
                for (int q = 0; q < 8; q++) a[q] += bf2f(v3[q]);
            }
            j += 4;
        }
        float di = dis[node];
        usx8 ov;
#pragma unroll
        for (int q = 0; q < 8; q++) {
            float val = bf2f(bv[q]) + di * a[q];
            ov[q] = f2bf(val);
            float vr = bf2f(ov[q]);  // stats on stored bf16 value (matches col_stats)
            csum[q] += vr;
            csq[q] += vr * vr;
        }
        *(usx8*)(agg + (size_t)node * HDIM + colb) = ov;
    }
    int gidx = wv * 4 + grp;
    int rep = (blockIdx.x & 7) * 256;
    // reduce sums
#pragma unroll
    for (int q = 0; q < 8; q++) red[gidx * 128 + colb + q] = csum[q];
    __syncthreads();
    if (t < 128) {
        float s = 0.f;
#pragma unroll
        for (int g = 0; g < 16; g++) s += red[g * 128 + t];
        atomicAdd(&gsum8[rep + t], s);
    }
    __syncthreads();
#pragma unroll
    for (int q = 0; q < 8; q++) red[gidx * 128 + colb + q] = csq[q];
    __syncthreads();
    if (t < 128) {
        float s = 0.f;
#pragma unroll
        for (int g = 0; g < 16; g++) s += red[g * 128 + t];
        atomicAdd(&gsum8[rep + 128 + t], s);
    }
}

// ---------------- pooling (computes BN3 in-block, fused ReLU) ----------------
__global__ void pool(const unsigned short* __restrict__ hin, const int* __restrict__ goff,
                     const int* __restrict__ gcnt, const float* __restrict__ gsum3,
                     const unsigned short* __restrict__ gamma,
                     const unsigned short* __restrict__ beta, float* __restrict__ pooled,
                     float invn) {
    __shared__ float scs[128], shs[128];
    __shared__ float ls[256];
    int g = blockIdx.x, t = threadIdx.x;
    if (t < 128) {
        float s = 0.f, s2 = 0.f;
#pragma unroll
        for (int r = 0; r < 8; r++) {
            s += gsum3[r * 256 + t];
            s2 += gsum3[r * 256 + 128 + t];
        }
        float m = s * invn;
        float vv = s2 * invn - m * m;
        float sc = bf2f(gamma[t]) * rsqrtf(vv + 1e-5f);
        scs[t] = sc;
        shs[t] = bf2f(beta[t]) - m * sc;
    }
    __syncthreads();
    int c = t & 127, p = t >> 7;
    float scale = scs[c], shift = shs[c];
    int s = goff[g], cn = gcnt[g];
    float acc = 0.f;
    for (int r = s + p; r < s + cn; r += 2)
        acc += fmaxf(scale * bf2f(hin[(size_t)r * HDIM + c]) + shift, 0.f);
    ls[t] = acc;
    __syncthreads();
    if (t < 128) pooled[(size_t)g * HDIM + t] = (ls[t] + ls[t + 128]) / fmaxf((float)cn, 1.f);
}
__global__ void pooled_bn(const float* __restrict__ pooled, const unsigned short* __restrict__ g,
                          const unsigned short* __restrict__ be, float* __restrict__ psc,
                          float* __restrict__ psh, int G_) {
    int t = threadIdx.x;
    int c = t & 127, p = t >> 7;
    float s = 0.f, s2 = 0.f;
    for (int r = p; r < G_; r += 4) {
        float v = pooled[(size_t)r * HDIM + c];
        s += v;
        s2 += v * v;
    }
    __shared__ float ls[512], ls2[512];
    ls[t] = s;
    ls2[t] = s2;
    __syncthreads();
    if (t < 128) {
        float S = ls[t] + ls[t + 128] + ls[t + 256] + ls[t + 384];
        float S2 = ls2[t] + ls2[t + 128] + ls2[t + 256] + ls2[t + 384];
        float m = S / (float)G_;
        float v = S2 / (float)G_ - m * m;
        float sc = bf2f(g[t]) * rsqrtf(v + 1e-5f);
        psc[t] = sc;
        psh[t] = bf2f(be[t]) - m * sc;
    }
}
// ---------------- fused MLP head + log_softmax ----------------
__global__ void mlp12(const float* __restrict__ pooled, const float* __restrict__ psc,
                      const float* __restrict__ psh, const unsigned short* __restrict__ lw1,
                      const unsigned short* __restrict__ lb1,
                      const unsigned short* __restrict__ lw2,
                      const unsigned short* __restrict__ lb2, void* __restrict__ out,
                      const int* __restrict__ flags) {
    int r = blockIdx.x, t = threadIdx.x;
    __shared__ float row[128];
    __shared__ float z1s[128];
    __shared__ float z2[10];
    __shared__ float lse;
    row[t] = psc[t] * pooled[(size_t)r * HDIM + t] + psh[t];
    __syncthreads();
    float acc = bf2f(lb1[t]);
    for (int k = 0; k < 128; k++) acc += row[k] * bf2f(lw1[k * HDIM + t]);
    z1s[t] = fmaxf(acc, 0.f);
    __syncthreads();
    if (t < 10) {
        float a = bf2f(lb2[t]);
        for (int k = 0; k < 128; k++) a += z1s[k] * bf2f(lw2[k * 10 + t]);
        z2[t] = a;
    }
    __syncthreads();
    if (t == 0) {
        float m = z2[0];
        for (int j = 1; j < 10; j++) m = fmaxf(m, z2[j]);
        float s = 0.f;
        for (int j = 0; j < 10; j++) s += expf(z2[j] - m);
        lse = m + logf(s);
    }
    __syncthreads();
    if (t < 10) {
        float v = z2[t] - lse;
        if (flags[0]) ((unsigned short*)out)[r * 10 + t] = f2bf(v);
        else ((float*)out)[r * 10 + t] = v;
    }
}

extern "C" void kernel_launch(void* const* d_in, const int* in_sizes, int n_in,
                              void* d_out, int out_size, void* d_ws, size_t ws_size,
                              hipStream_t stream) {
    const void* x = d_in[0];
    const void* ei = d_in[1];
    const void* batch = d_in[2];

    int N_ = in_sizes[2];
    int E_ = in_sizes[1] / 2;
    int G_ = out_size / 10;

    const int TILE = 4096;  // ntiles <= 512 required by s1_scan (E<=2M)
    int NB = (N_ + 511) / 512;  // <=256 required by in-kernel base scans
    int ntiles = (E_ + TILE - 1) / TILE;
    int L = NB * ntiles;

    char* ws = (char*)d_ws;
    auto alloc = [&](size_t bytes) -> char* {
        char* p = ws;
        ws += (bytes + 255) & ~(size_t)255;
        return p;
    };
    int* flags = (int*)alloc(256);
    float* dis = (float*)alloc((size_t)N_ * 4);
    int* offs = (int*)alloc((size_t)N_ * 4);
    int* cnt = (int*)alloc((size_t)N_ * 4);
    int* Ct = (int*)alloc((size_t)L * 4);
    int* btot = (int*)alloc(1024);
    unsigned int* pairs = (unsigned int*)alloc((size_t)E_ * 4);
    int* csrc = (int*)alloc((size_t)E_ * 4);
    unsigned short* hw = (unsigned short*)alloc((size_t)N_ * HDIM * 2);
    unsigned short* aggbuf = (unsigned short*)alloc((size_t)N_ * HDIM * 2);
    unsigned short* wconv = (unsigned short*)alloc(70000 * 2);
    unsigned short* wfrag = (unsigned short*)alloc(3 * HDIM * HDIM * 2);
    float* gsumAll = (float*)alloc(6144 * 4);  // 3 layers x 8 replicas x (128 sum + 128 sq)
    int* gcnt = (int*)alloc((size_t)G_ * 4);
    int* goff = (int*)alloc((size_t)G_ * 4);
    float* pooled = (float*)alloc((size_t)G_ * HDIM * 4);
    float* psc = (float*)alloc(128 * 4);
    float* psh = (float*)alloc(128 * 4);

    // wconv layout (element offsets)
    const int oB = 49152;
    const int oLB1 = oB + 1408;
    const int oLW1 = oLB1 + 128;
    const int oLW2 = oLW1 + 16384;
    const int oLB2 = oLW2 + 1280;

    ParamTab tab;
    const int srcIdx[15] = {4, 5, 6, 8, 9, 10, 12, 13, 14, 15, 16, 18, 17, 19, 20};
    const int dstOff[15] = {oB + 0, oB + 128, oB + 256,
                            oB + 384, oB + 512, oB + 640,
                            oB + 768, oB + 896, oB + 1024,
                            oB + 1152, oB + 1280,
                            oLB1, oLW1, oLW2, oLB2};
    for (int i = 0; i < 15; i++) {
        tab.p[i] = d_in[srcIdx[i]];
        tab.n[i] = in_sizes[srcIdx[i]];
        tab.off[i] = dstOff[i];
    }

    int p1_grid = ntiles + 15 + 2 + 24 + 1;
    phase1<<<p1_grid, 256, 0, stream>>>((const unsigned int*)x, (const unsigned int*)ei, ei,
                                        batch, d_in[3], d_in[7], d_in[11], tab, flags, gsumAll,
                                        Ct, wconv, wfrag, goff, gcnt, E_, N_, G_, NB, ntiles,
                                        TILE);
    s1_scan<<<NB, 512, 0, stream>>>(Ct, btot, NB, ntiles);
    p1_scatter<<<ntiles, 256, 0, stream>>>(ei, flags, Ct, btot, pairs, E_, NB, ntiles, TILE);
    p2_build<<<NB, 256, 0, stream>>>(pairs, btot, csrc, offs, cnt, dis, E_, N_, NB);

    int mm_blocks = (((N_ + 15) / 16) * 64 + 255) / 256;
    float invn = 1.f / (float)N_;

    for (int l = 0; l < 3; l++) {
        const void* A = (l == 0) ? x : (const void*)aggbuf;
        const float* gp = (l == 0) ? nullptr : (gsumAll + (size_t)(l - 1) * 2048);
        const unsigned short* gam = wconv + oB + (l ? (l - 1) * 384 + 128 : 0);
        const unsigned short* bet = wconv + oB + (l ? (l - 1) * 384 + 256 : 0);
        mm_mfma<<<mm_blocks, 256, 0, stream>>>(A, wfrag + (size_t)l * HDIM * HDIM, hw, N_, gp,
                                               gam, bet, dis, flags, (l == 0) ? 1 : 0, invn);
        aggregate<<<768, 256, 0, stream>>>(hw, dis, offs, cnt, csrc, wconv + oB + l * 384,
                                           aggbuf, gsumAll + (size_t)l * 2048, N_);
    }

    pool<<<G_, 256, 0, stream>>>(aggbuf, goff, gcnt, gsumAll + 2 * 2048,
                                 wconv + oB + 2 * 384 + 128, wconv + oB + 2 * 384 + 256, pooled,
                                 invn);
    pooled_bn<<<1, 512, 0, stream>>>(pooled, wconv + oB + 1152, wconv + oB + 1280, psc, psh, G_);
    mlp12<<<G_, 128, 0, stream>>>(pooled, psc, psh, wconv + oLW1, wconv + oLB1, wconv + oLW2,
                                  wconv + oLB2, d_out, flags);
}